// Round 1
// 257.443 us; speedup vs baseline: 1.0026x; 1.0026x over previous
//
#include <hip/hip_runtime.h>
#include <math.h>

// Problem constants (fixed by the reference)
#define NB 8
#define NC 9               // channels (== NUM_CLASSES)
#define PIXELS (768*768)   // 589824 pixels per batch image
#define BLOCK 256
#define PPT 8                          // pixels per thread (2 x int4) -> room for 64 one-hot regs
#define CHUNK_PX (BLOCK * PPT)         // 2048
#define NCHUNK (PIXELS / CHUNK_PX)     // 288 exactly
#define NITER (PPT / 4)                // 2 vector iterations
#define NWAVE (BLOCK / 64)
#define GRID (NB * NCHUNK)             // 2304 blocks = exactly 9 per CU
#define SLOT 80                        // per-block partial: 72 sums + 8 counts

// split-butterfly wave reduction: 8 class-sums partitioned across lanes.
// On return, lanes 0..7 hold the wave total for class cls = (p<<2)|(q<<1)|r.
__device__ __forceinline__ float butterfly8(const float s[8], int p, int q, int r)
{
    float u[4];
    #pragma unroll
    for (int j = 0; j < 4; ++j) {
        float x = p ? s[j] : s[j + 4];
        float y = __shfl_xor(x, 1, 64);
        u[j] = (p ? s[j + 4] : s[j]) + y;
    }
    float v2[2];
    #pragma unroll
    for (int j = 0; j < 2; ++j) {
        float x = q ? u[j] : u[j + 2];
        float y = __shfl_xor(x, 2, 64);
        v2[j] = (q ? u[j + 2] : u[j]) + y;
    }
    float w;
    {
        float x = r ? v2[0] : v2[1];
        float y = __shfl_xor(x, 4, 64);
        w = (r ? v2[1] : v2[0]) + y;
    }
    w += __shfl_xor(w, 8, 64);
    w += __shfl_xor(w, 16, 64);
    w += __shfl_xor(w, 32, 64);
    return w;
}

__global__ __launch_bounds__(BLOCK, 4)
void accum_kernel(const int* __restrict__ masks,
                  const float* __restrict__ outputs,
                  float* __restrict__ partial)   // [GRID][SLOT]
{
    int blk = blockIdx.x;
    int chunk = blk % NCHUNK;
    int b = blk / NCHUNK;
    int t = threadIdx.x;
    int wave = t >> 6;
    int lane = t & 63;

    // ---- load mask chunk ONCE ----
    const int4* __restrict__ m4 =
        (const int4*)(masks + (size_t)b * PIXELS + (size_t)chunk * CHUNK_PX);
    int4 m[NITER];
    #pragma unroll
    for (int i = 0; i < NITER; ++i) m[i] = m4[t + i * BLOCK];

    // ---- one-hot float masks, computed ONCE, reused by all 9 channels ----
    // fm[e][k] = 1.0f iff pixel e has class k+1. 64 VGPRs, paid 2 VALU ops each,
    // then every (elem,class,channel) accumulate is a single v_fmac_f32.
    float fm[PPT][8];
    #pragma unroll
    for (int i = 0; i < NITER; ++i) {
        int mv[4] = { m[i].x, m[i].y, m[i].z, m[i].w };
        #pragma unroll
        for (int e = 0; e < 4; ++e) {
            #pragma unroll
            for (int k = 0; k < 8; ++k)
                fm[i * 4 + e][k] = (mv[e] == k + 1) ? 1.0f : 0.0f;
        }
    }

    __shared__ float red[NC][NWAVE][8];   // per-channel per-wave class sums
    __shared__ float red_c[NWAVE][8];     // per-wave class counts

    const int p = lane & 1;
    const int q = (lane >> 1) & 1;
    const int r = (lane >> 2) & 1;

    // ---- counts: just the sum of the one-hot masks (exact small ints in fp32) ----
    {
        float cnt[8];
        #pragma unroll
        for (int k = 0; k < 8; ++k) cnt[k] = 0.f;
        #pragma unroll
        for (int e = 0; e < PPT; ++e) {
            #pragma unroll
            for (int k = 0; k < 8; ++k) cnt[k] += fm[e][k];
        }
        float w = butterfly8(cnt, p, q, r);
        if (lane < 8) red_c[wave][(p << 2) | (q << 1) | r] = w;
    }

    const float* outbase = outputs + (size_t)b * NC * PIXELS + (size_t)chunk * CHUNK_PX;

    // ---- per-channel accumulation: 1 fmac per (elem, class) ----
    #pragma unroll
    for (int c = 0; c < NC; ++c) {
        const float4* o4 = (const float4*)(outbase + (size_t)c * PIXELS);
        float4 buf[NITER];
        #pragma unroll
        for (int i = 0; i < NITER; ++i) buf[i] = o4[t + i * BLOCK];

        float s[8];
        #pragma unroll
        for (int k = 0; k < 8; ++k) s[k] = 0.f;

        #pragma unroll
        for (int i = 0; i < NITER; ++i) {
            float v[4] = { buf[i].x, buf[i].y, buf[i].z, buf[i].w };
            #pragma unroll
            for (int e = 0; e < 4; ++e) {
                #pragma unroll
                for (int k = 0; k < 8; ++k)
                    s[k] = fmaf(fm[i * 4 + e][k], v[e], s[k]);
            }
        }

        float w = butterfly8(s, p, q, r);
        if (lane < 8) red[c][wave][(p << 2) | (q << 1) | r] = w;
    }

    __syncthreads();

    // ---- slot write: NO atomics, NO zero-init needed ----
    if (t < NC * 8) {                 // col = c*8 + k
        int c = t >> 3;
        int k = t & 7;
        float tot = 0.f;
        #pragma unroll
        for (int w = 0; w < NWAVE; ++w) tot += red[c][w][k];
        partial[(size_t)blk * SLOT + c * 8 + k] = tot;
    } else if (t < NC * 8 + 8) {      // col = 72 + k : class counts
        int k = t - NC * 8;
        float tot = 0.f;
        #pragma unroll
        for (int w = 0; w < NWAVE; ++w) tot += red_c[w][k];
        partial[(size_t)blk * SLOT + 72 + k] = tot;
    }
}

__global__ __launch_bounds__(1024)
void finalize_kernel(const float* __restrict__ partial,  // [GRID][SLOT]
                     float* __restrict__ out)
{
    __shared__ float tot[NB][SLOT];
    int t = threadIdx.x;

    // 640 threads: each reduces one (batch, col) over that batch's 288 blocks
    if (t < NB * SLOT) {
        int b = t / SLOT;
        int col = t % SLOT;
        const float* p = partial + (size_t)b * NCHUNK * SLOT + col;
        float s = 0.f;
        #pragma unroll 8
        for (int blk = 0; blk < NCHUNK; ++blk) s += p[(size_t)blk * SLOT];
        tot[b][col] = s;
    }
    __syncthreads();

    if (t < 64) {                    // one wave does the tiny math
        int b = t >> 3;
        int cls = t & 7;

        float cntv = tot[b][72 + cls];
        float denom = fmaxf(cntv, 1.0f);

        float pr[NC];
        float mx = -INFINITY;
        #pragma unroll
        for (int c = 0; c < NC; ++c) {
            pr[c] = tot[b][c * 8 + cls] / denom;
            mx = fmaxf(mx, pr[c]);
        }
        float se = 0.f;
        #pragma unroll
        for (int c = 0; c < NC; ++c) se += expf(pr[c] - mx);
        float lse = logf(se);

        float per = 0.f;
        #pragma unroll
        for (int c = 0; c < NC; ++c) {
            float tgt = (c == cls + 1) ? 0.9f : 0.0125f;
            per -= tgt * (pr[c] - mx - lse);
        }

        bool present = cntv > 0.f;
        float val = present ? per : 0.f;
        float np  = present ? 1.f : 0.f;
        #pragma unroll
        for (int off = 32; off > 0; off >>= 1) {
            val += __shfl_down(val, off, 64);
            np  += __shfl_down(np,  off, 64);
        }
        if (t == 0) out[0] = val / fmaxf(np, 1.f);
    }
}

extern "C" void kernel_launch(void* const* d_in, const int* in_sizes, int n_in,
                              void* d_out, int out_size, void* d_ws, size_t ws_size,
                              hipStream_t stream) {
    const int*   masks   = (const int*)d_in[0];
    const float* outputs = (const float*)d_in[1];
    float* partial = (float*)d_ws;   // GRID*SLOT floats = 720 KB, overwritten fully

    accum_kernel<<<GRID, BLOCK, 0, stream>>>(masks, outputs, partial);
    finalize_kernel<<<1, 1024, 0, stream>>>(partial, (float*)d_out);
}